// Round 6
// baseline (124.752 us; speedup 1.0000x reference)
//
#include <hip/hip_runtime.h>
#include <hip/hip_bf16.h>

#define NFFT   4194304
#define NMODES 2
#define NTAPS  101
#define NVALID (NFFT - NTAPS + 1)   // 4194204
#define N0     (NTAPS / 2)          // 50

constexpr int BLOCK = 256;                          // 4 waves
constexpr int TILE  = 2048;                         // output samples per block (512/wave)
constexpr int NT    = (NVALID + TILE - 1) / TILE;   // 2048 blocks, one tile each
constexpr int WIN   = 2176;                         // staged P samples (max read idx 2151)
constexpr int NM    = 15;                           // banded MFMA accumulation steps
constexpr int TWRD  = 136;                          // words per rotated B table
constexpr int NTAB  = 8;                            // tables: r(4) x o(2)

typedef __attribute__((ext_vector_type(8)))  short short8;
typedef __attribute__((ext_vector_type(16))) float float16;

static __device__ __forceinline__ unsigned short f2bf(float x) {
    __hip_bfloat16 h = __float2bfloat16(x);
    return *reinterpret_cast<unsigned short*>(&h);
}
static __device__ __forceinline__ unsigned pk(float e0, float e1) {
    return (unsigned)f2bf(e0) | ((unsigned)f2bf(e1) << 16);
}
// XOR word bits 2..4 with sample bits 5..7: keeps 16B alignment of 4-word groups,
// spreads the 64B-stride fragment reads across banks (residual 2-way = free).
static __device__ __forceinline__ int swz(int s) {
    return s ^ (((s >> 5) & 7) << 2);
}

__global__ __launch_bounds__(BLOCK, 8) void nl_kernel(
    const float* __restrict__ xa,   // d_in[0] big stream (A = xr)
    const float* __restrict__ xb,   // d_in[1] big stream (B = xi)
    const float* __restrict__ W,  const float* __restrict__ b,
    const float* __restrict__ power, unsigned* __restrict__ out)
{
    // Pl[swz(s)] = bf16x2 P sample s (mode0 low, mode1 high), 2176 words = 8.5 KB.
    __shared__ __align__(16) unsigned Pl[WIN];
    // Rotated B tables: Bt[(2r+o)*136 + 4q + d] = Bval(tau = 4q + r + d, o), where
    // Bval(tau,o) = pk(W[tau-15,0,o], W[tau-15,1,o]) for tau-15 in [0,100], else 0.
    // Gives each lane a 16B-aligned ds_read_b128 per m (tau0 & 3 is m-invariant).
    __shared__ __align__(16) unsigned Bt[NTAB * TWRD];   // 4.35 KB

    const int tid  = threadIdx.x;
    const int lane = tid & 63;
    const int wid  = tid >> 6;
    const int colc = lane & 31;      // B/C column = (c_s<<1)|o ; also A row index
    const int h    = lane >> 5;      // k half: k = 8h + e
    const int cs   = colc >> 1;      // fine shift 0..15
    const int o    = colc & 1;       // output mode
    const int r    = colc;           // A row

    const int tile_start = blockIdx.x * TILE;

    // ---- stage P = xa^2 + xb^2 as bf16x2 into swizzled LDS ----
    const float4* __restrict__ xa4 = reinterpret_cast<const float4*>(xa); // 2 samples
    const float4* __restrict__ xb4 = reinterpret_cast<const float4*>(xb);
    #pragma unroll
    for (int k = 0; k < 5; ++k) {
        const int s = 2 * tid + 512 * k;            // even
        if (k < 4 || s < WIN) {
            const int g = tile_start + s;
            float4 a = make_float4(0.f, 0.f, 0.f, 0.f), c = a;
            if (g < NFFT) { a = xa4[g >> 1]; c = xb4[g >> 1]; }
            const unsigned u0 = pk(a.x * a.x + c.x * c.x, a.y * a.y + c.y * c.y);
            const unsigned u1 = pk(a.z * a.z + c.z * c.z, a.w * a.w + c.w * c.w);
            *reinterpret_cast<uint2*>(&Pl[swz(s)]) = make_uint2(u0, u1);
        }
    }

    __builtin_amdgcn_sched_barrier(0);

    // ---- build rotated B tables: 1088 words, ~4.25 per thread ----
    {
        const float4* __restrict__ Wt = reinterpret_cast<const float4*>(W);
        for (int idx = tid; idx < NTAB * TWRD; idx += BLOCK) {
            const int tab = idx / TWRD;
            const int w   = idx - tab * TWRD;
            const int rr  = tab >> 1, oo = tab & 1;
            const int t   = (w & ~3) + rr + (w & 3) - 15;   // tau - 15
            const bool ok = (unsigned)t <= 100u;
            const float4 ww = Wt[ok ? t : 0];
            Bt[idx] = ok ? pk(oo ? ww.y : ww.x, oo ? ww.w : ww.z) : 0u;
        }
    }
    __builtin_amdgcn_sched_barrier(0);
    __syncthreads();

    // ---- per-wave 512-sample chunk: 15 x (b128 A + b128 B + 32x32x16 MFMA) ----
    // A_m[r][k=(dt,i)] = P[cb + 16r + 8m + dt, i]; lane (r,h) reads one aligned uint4.
    // B_m fragment = Bt[tb + 8m .. +3], tb = (2*rot+o)*136 + 4*q0, tau0 = 4h - cs + 15.
    const int cb   = wid * 512;
    const int tau0 = 4 * h - cs + 15;                 // in [0,19]
    const int tb   = (((tau0 & 3) << 1) | o) * TWRD + (tau0 >> 2) * 4;
    float16 acc = {};
    uint4 areg[4];                    // 4-deep A prefetch pipe (static idx post-unroll)
    #pragma unroll
    for (int m = 0; m < 4; ++m)
        areg[m] = *reinterpret_cast<const uint4*>(&Pl[swz(cb + 16 * r + 8 * m + 4 * h)]);
    #pragma unroll
    for (int m = 0; m < NM; ++m) {
        const uint4 bq = *reinterpret_cast<const uint4*>(&Bt[tb + 8 * m]);
        acc = __builtin_amdgcn_mfma_f32_32x32x16_bf16(
                  __builtin_bit_cast(short8, areg[m & 3]),
                  __builtin_bit_cast(short8, bq), acc, 0, 0, 0);
        if (m + 4 < NM)
            areg[m & 3] = *reinterpret_cast<const uint4*>(
                              &Pl[swz(cb + 16 * r + 8 * (m + 4) + 4 * h)]);
    }

    // ---- epilogue: straight from accumulators; one base, immediate offsets ----
    // C/D: col = lane&31, row = (reg&3) + 8*(reg>>2) + 4*(lane>>5);
    // x/out word idx = ibase + 32*row, 32*row*4B <= 3968 fits the 13-bit imm offset.
    const float bo   = o ? b[1] : b[0];
    const float coef = 0.066268f * exp10f(power[0] * 0.1f);
    const int ibase  = 2 * (tile_start + cb + cs + N0) + o;
    const float* __restrict__ pxa = xa + ibase;
    const float* __restrict__ pxb = xb + ibase;
    unsigned* __restrict__ pou = out + (ibase - 2 * N0);

    if (blockIdx.x != NT - 1) {                       // full tile: branch-free
        #pragma unroll
        for (int j = 0; j < 16; ++j) {
            const int off = 32 * ((j & 3) + 8 * (j >> 2) + 4 * h);
            const float Ax = pxa[off];
            const float Bx = pxb[off];
            float sn, cn;
            __sincosf((acc[j] + bo) * coef, &sn, &cn);
            __builtin_nontemporal_store(pk(Bx * cn - Ax * sn, Ax * cn + Bx * sn),
                                        &pou[off]);
        }
    } else {                                          // tail tile: guarded
        #pragma unroll
        for (int j = 0; j < 16; ++j) {
            const int row = (j & 3) + 8 * (j >> 2) + 4 * h;
            const int n   = tile_start + cb + 16 * row + cs;
            if (n < NVALID) {
                const float Ax = xa[(n + N0) * 2 + o];
                const float Bx = xb[(n + N0) * 2 + o];
                float sn, cn;
                __sincosf((acc[j] + bo) * coef, &sn, &cn);
                __builtin_nontemporal_store(pk(Bx * cn - Ax * sn, Ax * cn + Bx * sn),
                                            &out[n * 2 + o]);
            }
        }
    }
}

extern "C" void kernel_launch(void* const* d_in, const int* in_sizes, int n_in,
                              void* d_out, int out_size, void* d_ws, size_t ws_size,
                              hipStream_t stream) {
    // Bind by size (robust): big arrays = x streams, 404 = W, 2 = b, 1 = power.
    const float* big[2] = {nullptr, nullptr};
    const float* W = nullptr; const float* b = nullptr; const float* power = nullptr;
    int nbig = 0;
    for (int i = 0; i < n_in; ++i) {
        const float* p = (const float*)d_in[i];
        const int sz = in_sizes[i];
        if (sz == NFFT * NMODES)       { if (nbig < 2) big[nbig++] = p; }
        else if (sz == NTAPS * NMODES * NMODES) { W = p; }
        else if (sz == NMODES)         { b = p; }
        else if (sz == 1)              { power = p; }
    }

    unsigned* out = (unsigned*)d_out;
    nl_kernel<<<NT, BLOCK, 0, stream>>>(big[0], big[1], W, b, power, out);
}